// Round 1
// baseline (95.309 us; speedup 1.0000x reference)
//
#include <hip/hip_runtime.h>

// Depth-4 path signature, C=10 channels, L=64, per-block batch element.
// Horner-form Chen update per increment dx:
//   U1 = S1 + dx/4 ; U2 = S2 + U1 (x) dx /3 ; U3 = S3 + U2 (x) dx /2
//   S4' = S4 + U3 (x) dx
//   V1 = S1 + dx/3 ; V2 = S2 + V1 (x) dx /2 ; S3' = S3 + V2 (x) dx
//   S2' = S2 + (S1 + dx/2) (x) dx ; S1' = S1 + dx
// Ownership: S1 replicated; S2[t] owned by thread t<100 (i=t/10, j=t%10);
// S3[n], S4[n][0..9] owned for n = t + 250q (q=0..3), t<250.
// U2/V2 broadcast via LDS. Output staged through LDS for coalesced stores.

constexpr int C = 10;
constexpr int L = 64;
constexpr int NSTEP = L - 1;                      // 63
constexpr int OUTSZ = 10 + 100 + 1000 + 10000;    // 11110

__global__ __launch_bounds__(256) void sig4_kernel(
    const float* __restrict__ x, float* __restrict__ out)
{
    const int b = blockIdx.x;
    const int t = threadIdx.x;
    const float* __restrict__ xb = x + (size_t)b * (C * L);

    __shared__ float smem[2816];
    float* dxs = smem;          // [63*10] increments
    float* u2s = smem + 640;    // [100]
    float* v2s = smem + 740;    // [100]
    float* pl  = smem + 840;    // [640] path (init only)

    // coalesced path load
    for (int i = t; i < C * L; i += 256) pl[i] = xb[i];
    __syncthreads();
    // increments: dx[s][c] = path[c][s+1] - path[c][s]
    for (int i = t; i < NSTEP * C; i += 256) {
        int s = i / C, c = i % C;
        dxs[i] = pl[c * L + s + 1] - pl[c * L + s];
    }
    __syncthreads();

    // state registers
    float s1[C];
    float s2 = 0.f;
    float s3[4] = {0.f, 0.f, 0.f, 0.f};
    float s4[4][C];
    #pragma unroll
    for (int c = 0; c < C; ++c) s1[c] = 0.f;
    #pragma unroll
    for (int q = 0; q < 4; ++q) {
        #pragma unroll
        for (int l = 0; l < C; ++l) s4[q][l] = 0.f;
    }

    const int tdiv = t / 10;   // S2 owner: i ; triple owner: ij base (0..24)
    const int tmod = t % 10;   // S2 owner: j ; triple owner: k

    for (int s = 0; s < NSTEP; ++s) {
        float dx[C];
        #pragma unroll
        for (int c = 0; c < C; ++c) dx[c] = dxs[s * C + c];

        if (t < 100) {
            // uses OLD s1, s2; then update s2, s1
            float dj = dx[tmod];
            float di = dx[tdiv];
            float s1i = s1[tdiv];
            float u1 = s1i + di * 0.25f;
            float v1 = s1i + di * (1.f / 3.f);
            float w1 = s1i + di * 0.5f;
            u2s[t] = s2 + u1 * dj * (1.f / 3.f);
            v2s[t] = s2 + v1 * dj * 0.5f;
            s2 += w1 * dj;
            #pragma unroll
            for (int c = 0; c < C; ++c) s1[c] += dx[c];
        }
        __syncthreads();
        if (t < 250) {
            float dk = dx[tmod];
            #pragma unroll
            for (int q = 0; q < 4; ++q) {
                float u2 = u2s[tdiv + 25 * q];
                float v2 = v2s[tdiv + 25 * q];
                float u3 = s3[q] + u2 * dk * 0.5f;
                s3[q] += v2 * dk;
                #pragma unroll
                for (int l = 0; l < C; ++l) s4[q][l] += u3 * dx[l];
            }
        }
        __syncthreads();
    }

    // ---- epilogue ----
    float* __restrict__ ob = out + (size_t)b * OUTSZ;
    if (t < 10)  ob[t] = s1[t];
    if (t < 100) ob[10 + t] = s2;
    if (t < 250) {
        #pragma unroll
        for (int q = 0; q < 4; ++q) ob[110 + 250 * q + t] = s3[q];  // coalesced
    }
    // S4 staged through LDS (stride 11 to avoid bank conflicts), chunk q covers
    // triples n = 250q + tt -> out flat [1110 + 2500q .. +2500), fully coalesced.
    float* stage = smem;  // 250*11 = 2750 floats
    for (int q = 0; q < 4; ++q) {
        __syncthreads();
        if (t < 250) {
            #pragma unroll
            for (int l = 0; l < C; ++l) stage[t * 11 + l] = s4[q][l];
        }
        __syncthreads();
        for (int i = t; i < 2500; i += 256) {
            int n = i / 10, l = i - n * 10;
            ob[1110 + 2500 * q + i] = stage[n * 11 + l];
        }
    }
}

extern "C" void kernel_launch(void* const* d_in, const int* in_sizes, int n_in,
                              void* d_out, int out_size, void* d_ws, size_t ws_size,
                              hipStream_t stream) {
    const float* x = (const float*)d_in[0];
    float* out = (float*)d_out;
    const int batch = in_sizes[0] / (C * L);   // 2048
    sig4_kernel<<<dim3(batch), dim3(256), 0, stream>>>(x, out);
}

// Round 2
// 59.580 us; speedup vs baseline: 1.5997x; 1.5997x over previous
//
#include <hip/hip_runtime.h>

// Depth-4 path signature, C=10, L=64. One block (256 thr) per batch element.
// Horner Chen step (verified R0):
//   U1=S1+dx/4; U2=S2+U1(x)dx/3; U3=S3+U2(x)dx/2; S4+=U3(x)dx
//   V1=S1+dx/3; V2=S2+V1(x)dx/2; S3+=V2(x)dx; S2+=(S1+dx/2)(x)dx; S1+=dx
// Phase1 (t<100): owns S2[t] (scalar) and s1[t/10] (scalar s1i); computes
//   u2/v2 for step s+1 into double-buffered LDS table (software pipeline).
// Phase2 (t<250): owns triples n=t+250q (q=0..3): s3 in 2x f2, s4 in f2[4][5].
//   All math packed via v_pk_fma_f32; u3 broadcast via op_sel (no movs).
// One barrier per step. No dynamic register-array indexing anywhere.

typedef float f2 __attribute__((ext_vector_type(2)));
typedef float f4 __attribute__((ext_vector_type(4)));

constexpr int C = 10;
constexpr int L = 64;
constexpr int NSTEP = L - 1;                   // 63
constexpr int OUTSZ = 10 + 100 + 1000 + 10000; // 11110

__device__ __forceinline__ f2 pk_fma(f2 a, f2 b, f2 c) {
  f2 d;
  asm("v_pk_fma_f32 %0, %1, %2, %3" : "=v"(d) : "v"(a), "v"(b), "v"(c));
  return d;
}
__device__ __forceinline__ void pk_fma_acc(f2& acc, f2 a, f2 b) {
  asm("v_pk_fma_f32 %0, %1, %2, %0" : "+v"(acc) : "v"(a), "v"(b));
}
// acc += a.lo * b   (broadcast low half of a)
__device__ __forceinline__ void pk_fma_acc_blo(f2& acc, f2 a, f2 b) {
  asm("v_pk_fma_f32 %0, %1, %2, %0 op_sel:[0,0,0] op_sel_hi:[0,1,1]"
      : "+v"(acc) : "v"(a), "v"(b));
}
// acc += a.hi * b   (broadcast high half of a)
__device__ __forceinline__ void pk_fma_acc_bhi(f2& acc, f2 a, f2 b) {
  asm("v_pk_fma_f32 %0, %1, %2, %0 op_sel:[1,0,0] op_sel_hi:[1,1,1]"
      : "+v"(acc) : "v"(a), "v"(b));
}

__global__ __launch_bounds__(256) void sig4_kernel(
    const float* __restrict__ x, float* __restrict__ out)
{
  const int b = blockIdx.x;
  const int t = threadIdx.x;
  const float* __restrict__ xb = x + (size_t)b * (C * L);

  __shared__ float smem[4096];
  float* dxs = smem;          // [63][16] padded rows, 16B-aligned
  float* uv0 = smem + 1008;   // [25][12]: u2 at [g][q], v2 at [g][4+q]
  float* uv1 = smem + 1308;
  float* pl  = smem + 1608;   // [640] path (init only)

  for (int i = t; i < C * L; i += 256) pl[i] = xb[i];
  __syncthreads();
  for (int i = t; i < NSTEP * C; i += 256) {
    int s = i / C, c = i - s * C;
    dxs[s * 16 + c] = pl[c * L + s + 1] - pl[c * L + s];
  }
  __syncthreads();

  const int tdiv = t / 10;
  const int tmod = t - tdiv * 10;
  const int g = t % 25, qq = t / 25;   // phase-1 writer slot (t<100)

  float s1i = 0.f, s2v = 0.f;          // phase-1 state (t<100)
  f2 s3a = {0.f, 0.f}, s3b = {0.f, 0.f};
  f2 s4r[4][5];
  #pragma unroll
  for (int q = 0; q < 4; ++q)
    #pragma unroll
    for (int m = 0; m < 5; ++m) s4r[q][m] = f2{0.f, 0.f};

  auto phase1 = [&](int sp, float* ub) {
    float dj = dxs[sp * 16 + tmod];
    float di = dxs[sp * 16 + tdiv];
    float u1 = fmaf(di, 0.25f, s1i);
    float v1 = fmaf(di, 1.f / 3.f, s1i);
    float w1 = fmaf(di, 0.5f, s1i);
    ub[g * 12 + qq]     = fmaf(u1, dj * (1.f / 3.f), s2v);
    ub[g * 12 + 4 + qq] = fmaf(v1, dj * 0.5f, s2v);
    s2v = fmaf(w1, dj, s2v);
    s1i += di;
  };

  if (t < 100) phase1(0, uv0);
  __syncthreads();

  for (int s = 0; s < NSTEP; ++s) {
    float* ub = (s & 1) ? uv1 : uv0;
    float* un = (s & 1) ? uv0 : uv1;
    if (t < 100 && s + 1 < NSTEP) phase1(s + 1, un);  // pipeline next step
    if (t < 250) {
      const float* dxr = dxs + s * 16;
      f4 d03 = *(const f4*)(dxr);          // wave-uniform broadcast reads
      f4 d47 = *(const f4*)(dxr + 4);
      f2 d89 = *(const f2*)(dxr + 8);
      float dk = dxr[tmod];
      const float* uvp = ub + tdiv * 12;
      f4 u2v = *(const f4*)(uvp);
      f4 v2v = *(const f4*)(uvp + 4);
      f2 dk2 = {dk, dk};
      f2 dkh = {dk * 0.5f, dk * 0.5f};
      f2 u2a = {u2v.x, u2v.y}, u2b = {u2v.z, u2v.w};
      f2 v2a = {v2v.x, v2v.y}, v2b = {v2v.z, v2v.w};
      f2 u3a = pk_fma(u2a, dkh, s3a);      // u3 for q=0,1
      f2 u3b = pk_fma(u2b, dkh, s3b);      // u3 for q=2,3
      pk_fma_acc(s3a, v2a, dk2);
      pk_fma_acc(s3b, v2b, dk2);
      f2 dp[5] = {{d03.x, d03.y}, {d03.z, d03.w},
                  {d47.x, d47.y}, {d47.z, d47.w}, d89};
      #pragma unroll
      for (int m = 0; m < 5; ++m) {
        pk_fma_acc_blo(s4r[0][m], u3a, dp[m]);
        pk_fma_acc_bhi(s4r[1][m], u3a, dp[m]);
        pk_fma_acc_blo(s4r[2][m], u3b, dp[m]);
        pk_fma_acc_bhi(s4r[3][m], u3b, dp[m]);
      }
    }
    __syncthreads();
  }

  // ---- epilogue ----
  float* __restrict__ ob = out + (size_t)b * OUTSZ;
  if (t < 100 && tmod == 0) ob[tdiv] = s1i;
  if (t < 100) ob[10 + t] = s2v;
  if (t < 250) {
    ob[110 + t]       = s3a.x;
    ob[110 + 250 + t] = s3a.y;
    ob[110 + 500 + t] = s3b.x;
    ob[110 + 750 + t] = s3b.y;
  }
  // S4: stage per-q through LDS (stride 12, f2), then coalesced f2 stores.
  float* stage = smem;  // 250*12 = 3000 floats
  for (int q = 0; q < 4; ++q) {
    __syncthreads();
    if (t < 250) {
      f2* spp = (f2*)(stage + t * 12);
      #pragma unroll
      for (int m = 0; m < 5; ++m) spp[m] = s4r[q][m];
    }
    __syncthreads();
    for (int i = t; i < 1250; i += 256) {
      int w = 2 * i;                 // even word offset in 2500-word region
      int n = w / 10, l = w - n * 10; // l in {0,2,4,6,8}: never crosses a row
      f2 v = *(const f2*)(stage + n * 12 + l);
      *(f2*)(ob + 1110 + 2500 * q + w) = v;
    }
  }
}

extern "C" void kernel_launch(void* const* d_in, const int* in_sizes, int n_in,
                              void* d_out, int out_size, void* d_ws, size_t ws_size,
                              hipStream_t stream) {
  const float* x = (const float*)d_in[0];
  float* out = (float*)d_out;
  const int batch = in_sizes[0] / (C * L);  // 2048
  sig4_kernel<<<dim3(batch), dim3(256), 0, stream>>>(x, out);
}